// Round 7
// baseline (557.942 us; speedup 1.0000x reference)
//
#include <hip/hip_runtime.h>

#define E_N 1600000
#define N_N 100000
#define SCAN_B 98  // ceil(N_N/1024)

// d_ws float-offset layout
#define OFF_B0F  0
#define OFF_B1F  64
#define OFF_B2F  128
#define OFF_FR0  192       // inner layer0 A-frags: 2048 bf16
#define OFF_FR1  1216      // 4096 bf16
#define OFF_FR2  3264      // 4096 bf16
#define OFF_FE0  5312      // end-layer0 A-frags: 12288 bf16
#define OFF_YBF  11456     // N*80 bf16
#define OFF_YACC 4011456   // N*64 fp32 agg accumulator; zperm (E floats) aliases it after node_kernel
#define OFF_CNT  10411456  // N ints (in-degree histogram)
#define OFF_CUR  10511456  // 100352 ints (exclusive offsets -> scatter cursor)
#define OFF_BSUM 10611808  // 128 ints
#define OFF_SRCS 10611936  // E ints (src, dst-sorted order)
#define OFF_DSTS 12211936  // E ints (dst, sorted ascending)
#define OFF_IPOS 13811936  // E ints (e -> sorted position)
// total = 15,411,936 floats ≈ 61.6 MB

#define STR 72   // inner LDS activation row stride (bf16)
#define OSTR 104 // edge_out LDS diff row stride (bf16)

// Wave-private LDS ordering: tiles are per-wave, so a full block barrier is
// overkill; same-wave DS ops only need the lgkm counter drained.
#define WAVE_SYNC() __asm__ volatile("s_waitcnt lgkmcnt(0)" ::: "memory")

typedef __attribute__((ext_vector_type(8))) short bf16x8;
typedef __attribute__((ext_vector_type(4))) float f32x4;

static __device__ __forceinline__ float b2f(unsigned short u) {
  union { unsigned int i; float f; } c; c.i = ((unsigned int)u) << 16; return c.f;
}
static __device__ __forceinline__ unsigned short f2b(float f) {
  union { float f; unsigned int i; } c; c.f = f;
  unsigned int r = c.i + 0x7FFFu + ((c.i >> 16) & 1u);  // RNE
  return (unsigned short)(r >> 16);
}
static __device__ __forceinline__ unsigned int pack2(float a, float b) {
  return (unsigned int)f2b(a) | ((unsigned int)f2b(b) << 16);
}

__global__ void prep_kernel(
    const float* __restrict__ w0, const float* __restrict__ b0, const float* __restrict__ g0,
    const float* __restrict__ be0, const float* __restrict__ m0, const float* __restrict__ v0,
    const float* __restrict__ w1, const float* __restrict__ b1, const float* __restrict__ g1,
    const float* __restrict__ be1, const float* __restrict__ m1, const float* __restrict__ v1,
    const float* __restrict__ w2, const float* __restrict__ b2, const float* __restrict__ g2,
    const float* __restrict__ be2, const float* __restrict__ m2, const float* __restrict__ v2,
    const float* __restrict__ we0, float* __restrict__ ws) {
  __shared__ float s0[64], s1[64], s2[64];
  int t = threadIdx.x;
  if (t < 64) {
    s0[t] = g0[t] * rsqrtf(v0[t] + 1e-5f);
    s1[t] = g1[t] * rsqrtf(v1[t] + 1e-5f);
    s2[t] = g2[t] * rsqrtf(v2[t] + 1e-5f);
    ws[OFF_B0F + t] = (b0[t] - m0[t]) * s0[t] + be0[t];
    ws[OFF_B1F + t] = (b1[t] - m1[t]) * s1[t] + be1[t];
    ws[OFF_B2F + t] = (b2[t] - m2[t]) * s2[t] + be2[t];
  }
  __syncthreads();
  unsigned short* fr0 = (unsigned short*)(ws + OFF_FR0);
  unsigned short* fr1 = (unsigned short*)(ws + OFF_FR1);
  unsigned short* fr2 = (unsigned short*)(ws + OFF_FR2);
  for (int i = t; i < 2048; i += 256) {  // layer0: KS=1
    int j = i & 7, lane = (i >> 3) & 63, mt = i >> 9;
    int f = mt * 16 + (lane & 15);
    int k = (lane >> 4) * 8 + j;
    fr0[i] = f2b(w0[k * 64 + f] * s0[f]);
  }
  for (int i = t; i < 4096; i += 256) {  // layer1: KS=2
    int j = i & 7, lane = (i >> 3) & 63, tile = i >> 9;
    int mt = tile >> 1, ks = tile & 1;
    int f = mt * 16 + (lane & 15);
    int k = ks * 32 + (lane >> 4) * 8 + j;
    fr1[i] = f2b(w1[k * 64 + f] * s1[f]);
  }
  for (int i = t; i < 4096; i += 256) {  // layer2: KS=2
    int j = i & 7, lane = (i >> 3) & 63, tile = i >> 9;
    int mt = tile >> 1, ks = tile & 1;
    int f = mt * 16 + (lane & 15);
    int k = ks * 32 + (lane >> 4) * 8 + j;
    fr2[i] = f2b(w2[k * 64 + f] * s2[f]);
  }
  unsigned short* fe0 = (unsigned short*)(ws + OFF_FE0);
  for (int i = t; i < 12288; i += 256) {
    int j = i & 7, lane = (i >> 3) & 63, tile = i >> 9;  // tile = mt*3+ks
    int mt = tile / 3, ks = tile - mt * 3;
    int h = mt * 16 + (lane & 15);
    int k = ks * 32 + ((lane >> 4) & 3) * 8 + j;
    fe0[i] = (k < 80) ? f2b(we0[k * 128 + h]) : (unsigned short)0;
  }
}

// ---------- dst-sort pipeline ----------
__global__ __launch_bounds__(256) void hist_kernel(const int* __restrict__ ei,
                                                   int* __restrict__ counts) {
  int e = blockIdx.x * 256 + threadIdx.x;
  if (e < E_N) atomicAdd(&counts[ei[E_N + e]], 1);
}

__global__ __launch_bounds__(1024) void scan1_kernel(const int* __restrict__ counts,
                                                     int* __restrict__ cursor,
                                                     int* __restrict__ bsum) {
  __shared__ int s[1024];
  int t = threadIdx.x;
  int i = blockIdx.x * 1024 + t;
  int v = (i < N_N) ? counts[i] : 0;
  s[t] = v;
  __syncthreads();
  for (int off = 1; off < 1024; off <<= 1) {
    int a = (t >= off) ? s[t - off] : 0;
    __syncthreads();
    s[t] += a;
    __syncthreads();
  }
  cursor[i] = s[t] - v;  // block-local exclusive
  if (t == 1023) bsum[blockIdx.x] = s[1023];
}

__global__ __launch_bounds__(128) void scan2_kernel(int* __restrict__ bsum) {
  __shared__ int s[128];
  int t = threadIdx.x;
  int v = (t < SCAN_B) ? bsum[t] : 0;
  s[t] = v;
  __syncthreads();
  for (int off = 1; off < 128; off <<= 1) {
    int a = (t >= off) ? s[t - off] : 0;
    __syncthreads();
    s[t] += a;
    __syncthreads();
  }
  if (t < SCAN_B) bsum[t] = s[t] - v;  // exclusive block bases
}

__global__ __launch_bounds__(1024) void scan3_kernel(int* __restrict__ cursor,
                                                     const int* __restrict__ bsum) {
  int i = blockIdx.x * 1024 + threadIdx.x;
  cursor[i] += bsum[blockIdx.x];
}

// R5 form (two independent 4B stores -> more MLP than one dependent 8B store;
// measured 113 vs 134 us) + nontemporal hints (lines are touched once).
__global__ __launch_bounds__(256) void scatter_kernel(const int* __restrict__ ei,
                                                      int* __restrict__ cursor,
                                                      int* __restrict__ srcs,
                                                      int* __restrict__ dsts,
                                                      int* __restrict__ ipos) {
  int e = blockIdx.x * 256 + threadIdx.x;
  if (e >= E_N) return;
  int s = ei[e], d = ei[E_N + e];
  int pos = atomicAdd(&cursor[d], 1);
  __builtin_nontemporal_store(s, &srcs[pos]);
  __builtin_nontemporal_store(d, &dsts[pos]);
  __builtin_nontemporal_store(pos, &ipos[e]);
}

// ---------- inner MLP (MFMA), edges in dst-sorted order ----------
template <int KS>
static __device__ __forceinline__ void mfma_layer(
    unsigned short* A, const unsigned short* __restrict__ frag,
    const float* __restrict__ bias, int lane) {
  const int m = lane & 15;
  const int quad = lane >> 4;
  bf16x8 wf[4][KS];
#pragma unroll
  for (int mt = 0; mt < 4; ++mt)
#pragma unroll
    for (int ks = 0; ks < KS; ++ks)
      wf[mt][ks] = *(const bf16x8*)(frag + (((mt * KS + ks) * 64) + lane) * 8);
  f32x4 binit[4];
#pragma unroll
  for (int mt = 0; mt < 4; ++mt)
    binit[mt] = *(const f32x4*)(bias + mt * 16 + quad * 4);
  f32x4 acc[4][4];
#pragma unroll
  for (int mt = 0; mt < 4; ++mt)
#pragma unroll
    for (int nt = 0; nt < 4; ++nt) acc[mt][nt] = binit[mt];
#pragma unroll
  for (int nt = 0; nt < 4; ++nt) {
#pragma unroll
    for (int ks = 0; ks < KS; ++ks) {
      bf16x8 bfr = *(const bf16x8*)(A + (nt * 16 + m) * STR + ks * 32 + quad * 8);
#pragma unroll
      for (int mt = 0; mt < 4; ++mt)
        acc[mt][nt] = __builtin_amdgcn_mfma_f32_16x16x32_bf16(wf[mt][ks], bfr, acc[mt][nt], 0, 0, 0);
    }
  }
  WAVE_SYNC();  // tile is wave-private: drain reads before overwrite
#pragma unroll
  for (int mt = 0; mt < 4; ++mt) {
#pragma unroll
    for (int nt = 0; nt < 4; ++nt) {
      f32x4 a = acc[mt][nt];
      uint2 p;
      p.x = pack2(fmaxf(a.x, 0.f), fmaxf(a.y, 0.f));
      p.y = pack2(fmaxf(a.z, 0.f), fmaxf(a.w, 0.f));
      *(uint2*)(A + (nt * 16 + m) * STR + mt * 16 + quad * 4) = p;
    }
  }
  WAVE_SYNC();
}

__global__ __launch_bounds__(256) void edge_inner_kernel(
    const float* __restrict__ x, const int* __restrict__ srcs, const int* __restrict__ dsts,
    const float* __restrict__ ws, float* __restrict__ yacc) {
  __shared__ unsigned short act[4][64 * STR];
  __shared__ int sdst[256];
  const int tid = threadIdx.x;
  const int w = tid >> 6;
  const int lane = tid & 63;
  unsigned short* A = act[w];

  const int pos = blockIdx.x * 256 + tid;  // E_N % 256 == 0
  const int src = srcs[pos];
  const int dst = dsts[pos];
  sdst[tid] = dst;  // read back only by the same wave

  const float4* x4 = (const float4*)x;
  float4 xi0 = x4[dst * 4 + 0], xi1 = x4[dst * 4 + 1], xi2 = x4[dst * 4 + 2], xi3 = x4[dst * 4 + 3];
  float4 xj0 = x4[src * 4 + 0], xj1 = x4[src * 4 + 1], xj2 = x4[src * 4 + 2], xj3 = x4[src * 4 + 3];
  float vi[16] = {xi0.x, xi0.y, xi0.z, xi0.w, xi1.x, xi1.y, xi1.z, xi1.w,
                  xi2.x, xi2.y, xi2.z, xi2.w, xi3.x, xi3.y, xi3.z, xi3.w};
  float vj[16] = {xj0.x, xj0.y, xj0.z, xj0.w, xj1.x, xj1.y, xj1.z, xj1.w,
                  xj2.x, xj2.y, xj2.z, xj2.w, xj3.x, xj3.y, xj3.z, xj3.w};
  unsigned int* row = (unsigned int*)(A + lane * STR);
#pragma unroll
  for (int q = 0; q < 8; ++q) row[q] = pack2(vi[2 * q], vi[2 * q + 1]);
#pragma unroll
  for (int q = 0; q < 8; ++q)
    row[8 + q] = pack2(vj[2 * q] - vi[2 * q], vj[2 * q + 1] - vi[2 * q + 1]);
  WAVE_SYNC();

  const unsigned short* fr0 = (const unsigned short*)(ws + OFF_FR0);
  const unsigned short* fr1 = (const unsigned short*)(ws + OFF_FR1);
  const unsigned short* fr2 = (const unsigned short*)(ws + OFF_FR2);
  mfma_layer<1>(A, fr0, ws + OFF_B0F, lane);
  mfma_layer<2>(A, fr1, ws + OFF_B1F, lane);
  mfma_layer<2>(A, fr2, ws + OFF_B2F, lane);

  // segment-reduce the wave's 64 sorted edges: one atomic row per dst-run
  const int base = w << 6;
  float sum = 0.f;
  int dprev = sdst[base];
  for (int eo = 0; eo < 64; ++eo) {
    int d = sdst[base + eo];  // wave-uniform
    if (d != dprev) {
      atomicAdd(&yacc[(size_t)dprev * 64 + lane], sum);
      sum = 0.f;
      dprev = d;
    }
    sum += b2f(A[eo * STR + lane]);
  }
  atomicAdd(&yacc[(size_t)dprev * 64 + lane], sum);
}

__global__ __launch_bounds__(256) void node_kernel(
    const float* __restrict__ yacc, const int* __restrict__ counts,
    const float* __restrict__ x, unsigned short* __restrict__ ybf) {
  int idx = blockIdx.x * 256 + threadIdx.x;
  if (idx >= N_N * 80) return;
  int n = idx / 80;
  int j = idx - n * 80;
  float v;
  if (j < 64) v = yacc[(size_t)n * 64 + j] / fmaxf((float)counts[n], 1.0f);
  else        v = x[n * 16 + (j - 64)];
  ybf[idx] = f2b(fmaxf(v, 0.f));
}

// MFMA end-MLP in sorted order; writes pre-sigmoid z coalesced to zperm
__global__ __launch_bounds__(256) void edge_out_kernel(
    const unsigned short* __restrict__ ybf,
    const int* __restrict__ srcs, const int* __restrict__ dsts,
    const unsigned short* __restrict__ fe0, const float* __restrict__ bee0,
    const float* __restrict__ we1, const float* __restrict__ bee1,
    float* __restrict__ zperm) {
  __shared__ unsigned short Dt[4][64 * OSTR];
  const int tid = threadIdx.x, w = tid >> 6, lane = tid & 63;
  const int quad = lane >> 4, m = lane & 15;
  unsigned short* Dw = Dt[w];
  const int pos = blockIdx.x * 256 + tid;
  const int src = srcs[pos], dst = dsts[pos];
  const bf16x8* ps = (const bf16x8*)(ybf + (size_t)src * 80);
  const bf16x8* pd = (const bf16x8*)(ybf + (size_t)dst * 80);
  uint4* drow = (uint4*)(Dw + lane * OSTR);
#pragma unroll
  for (int q = 0; q < 10; ++q) {  // 80 feats = 10 bf16x8 loads
    bf16x8 a = ps[q], b = pd[q];
    uint4 p;
    p.x = pack2(b2f((unsigned short)a[0]) - b2f((unsigned short)b[0]),
                b2f((unsigned short)a[1]) - b2f((unsigned short)b[1]));
    p.y = pack2(b2f((unsigned short)a[2]) - b2f((unsigned short)b[2]),
                b2f((unsigned short)a[3]) - b2f((unsigned short)b[3]));
    p.z = pack2(b2f((unsigned short)a[4]) - b2f((unsigned short)b[4]),
                b2f((unsigned short)a[5]) - b2f((unsigned short)b[5]));
    p.w = pack2(b2f((unsigned short)a[6]) - b2f((unsigned short)b[6]),
                b2f((unsigned short)a[7]) - b2f((unsigned short)b[7]));
    drow[q] = p;
  }
  { uint4 z; z.x = z.y = z.z = z.w = 0u; drow[10] = z; drow[11] = z; }  // pad k=80..95
  WAVE_SYNC();  // Dt[w] is wave-private

  bf16x8 bf[4][3];
#pragma unroll
  for (int nt = 0; nt < 4; ++nt)
#pragma unroll
    for (int ks = 0; ks < 3; ++ks)
      bf[nt][ks] = *(const bf16x8*)(Dw + (nt * 16 + m) * OSTR + ks * 32 + quad * 8);

  float fin[4] = {0.f, 0.f, 0.f, 0.f};
  for (int mt = 0; mt < 8; ++mt) {
    bf16x8 wf[3];
#pragma unroll
    for (int ks = 0; ks < 3; ++ks)
      wf[ks] = *(const bf16x8*)(fe0 + (size_t)(((mt * 3 + ks) * 64) + lane) * 8);
    f32x4 binit = *(const f32x4*)(bee0 + mt * 16 + quad * 4);
    float4 w1v = *(const float4*)(we1 + mt * 16 + quad * 4);
    f32x4 acc[4];
#pragma unroll
    for (int nt = 0; nt < 4; ++nt) acc[nt] = binit;
#pragma unroll
    for (int nt = 0; nt < 4; ++nt)
#pragma unroll
      for (int ks = 0; ks < 3; ++ks)
        acc[nt] = __builtin_amdgcn_mfma_f32_16x16x32_bf16(wf[ks], bf[nt][ks], acc[nt], 0, 0, 0);
#pragma unroll
    for (int nt = 0; nt < 4; ++nt) {
      f32x4 a = acc[nt];
      fin[nt] += fmaxf(a.x, 0.f) * w1v.x + fmaxf(a.y, 0.f) * w1v.y +
                 fmaxf(a.z, 0.f) * w1v.z + fmaxf(a.w, 0.f) * w1v.w;
    }
  }
#pragma unroll
  for (int nt = 0; nt < 4; ++nt) {
    float v = fin[nt];
    v += __shfl_xor(v, 16);
    v += __shfl_xor(v, 32);
    fin[nt] = v;
  }
  float z = (quad == 0) ? fin[0] : (quad == 1) ? fin[1] : (quad == 2) ? fin[2] : fin[3];
  zperm[pos] = z + bee1[0];
}

__global__ __launch_bounds__(256) void unperm_kernel(const float* __restrict__ zperm,
                                                     const int* __restrict__ ipos,
                                                     float* __restrict__ out) {
  int e = blockIdx.x * 256 + threadIdx.x;
  if (e >= E_N) return;
  float z = zperm[ipos[e]];
  out[e] = 1.0f / (1.0f + __expf(-z));
}

extern "C" void kernel_launch(void* const* d_in, const int* in_sizes, int n_in,
                              void* d_out, int out_size, void* d_ws, size_t ws_size,
                              hipStream_t stream) {
  const float* x   = (const float*)d_in[0];
  const int* ei    = (const int*)d_in[1];
  const float* w0  = (const float*)d_in[2];
  const float* b0  = (const float*)d_in[3];
  const float* g0  = (const float*)d_in[4];
  const float* be0 = (const float*)d_in[5];
  const float* m0  = (const float*)d_in[6];
  const float* v0  = (const float*)d_in[7];
  const float* w1  = (const float*)d_in[8];
  const float* b1  = (const float*)d_in[9];
  const float* g1  = (const float*)d_in[10];
  const float* be1 = (const float*)d_in[11];
  const float* m1  = (const float*)d_in[12];
  const float* v1  = (const float*)d_in[13];
  const float* w2  = (const float*)d_in[14];
  const float* b2  = (const float*)d_in[15];
  const float* g2  = (const float*)d_in[16];
  const float* be2 = (const float*)d_in[17];
  const float* m2  = (const float*)d_in[18];
  const float* v2  = (const float*)d_in[19];
  const float* we0 = (const float*)d_in[20];
  const float* bee0= (const float*)d_in[21];
  const float* we1 = (const float*)d_in[22];
  const float* bee1= (const float*)d_in[23];
  float* out = (float*)d_out;
  float* ws  = (float*)d_ws;

  int* counts = (int*)(ws + OFF_CNT);
  int* cursor = (int*)(ws + OFF_CUR);
  int* bsum   = (int*)(ws + OFF_BSUM);
  int* srcs   = (int*)(ws + OFF_SRCS);
  int* dsts   = (int*)(ws + OFF_DSTS);
  int* ipos   = (int*)(ws + OFF_IPOS);
  float* zperm = ws + OFF_YACC;  // aliases yacc: dead after node_kernel

  hipMemsetAsync(ws + OFF_YACC, 0, (size_t)N_N * 64 * sizeof(float), stream);
  hipMemsetAsync(counts, 0, (size_t)N_N * sizeof(int), stream);
  prep_kernel<<<1, 256, 0, stream>>>(w0, b0, g0, be0, m0, v0,
                                     w1, b1, g1, be1, m1, v1,
                                     w2, b2, g2, be2, m2, v2, we0, ws);
  hist_kernel<<<(E_N + 255) / 256, 256, 0, stream>>>(ei, counts);
  scan1_kernel<<<SCAN_B, 1024, 0, stream>>>(counts, cursor, bsum);
  scan2_kernel<<<1, 128, 0, stream>>>(bsum);
  scan3_kernel<<<SCAN_B, 1024, 0, stream>>>(cursor, bsum);
  scatter_kernel<<<(E_N + 255) / 256, 256, 0, stream>>>(ei, cursor, srcs, dsts, ipos);
  edge_inner_kernel<<<E_N / 256, 256, 0, stream>>>(x, srcs, dsts, ws, ws + OFF_YACC);
  node_kernel<<<(N_N * 80 + 255) / 256, 256, 0, stream>>>(ws + OFF_YACC, counts, x,
                                                          (unsigned short*)(ws + OFF_YBF));
  edge_out_kernel<<<E_N / 256, 256, 0, stream>>>((const unsigned short*)(ws + OFF_YBF),
                                                 srcs, dsts,
                                                 (const unsigned short*)(ws + OFF_FE0),
                                                 bee0, we1, bee1, zperm);
  unperm_kernel<<<(E_N + 255) / 256, 256, 0, stream>>>(zperm, ipos, out);
}

// Round 8
// 513.397 us; speedup vs baseline: 1.0868x; 1.0868x over previous
//
#include <hip/hip_runtime.h>

#define E_N 1600000
#define N_N 100000
#define SCAN_B 98  // ceil(N_N/1024)

// d_ws float-offset layout
#define OFF_B0F  0
#define OFF_B1F  64
#define OFF_B2F  128
#define OFF_FR0  192       // inner layer0 A-frags: 2048 bf16
#define OFF_FR1  1216      // 4096 bf16
#define OFF_FR2  3264      // 4096 bf16
#define OFF_FE0  5312      // end-layer0 A-frags: 12288 bf16
#define OFF_YBF  11456     // N*80 bf16
#define OFF_YACC 4011456   // N*64 fp32 agg accumulator; zperm (E floats) aliases it after node_kernel
#define OFF_CNT  10411456  // N ints (in-degree histogram)
#define OFF_CUR  10511456  // 100352 ints (exclusive offsets -> scatter cursor)
#define OFF_BSUM 10611808  // 128 ints
#define OFF_SRCS 10611936  // E ints (src, dst-sorted order)
#define OFF_DSTS 12211936  // E ints (dst, sorted ascending)
#define OFF_IPOS 13811936  // E ints (e -> sorted position)
// total = 15,411,936 floats ≈ 61.6 MB

#define STR 72   // inner LDS activation row stride (bf16)
#define OSTR 104 // edge_out LDS diff row stride (bf16)

// Wave-private LDS ordering: tiles are per-wave, so a full block barrier is
// overkill; same-wave DS ops only need the lgkm counter drained. (R7: neutral
// vs __syncthreads, kept for fewer stalls/instructions.)
#define WAVE_SYNC() __asm__ volatile("s_waitcnt lgkmcnt(0)" ::: "memory")

typedef __attribute__((ext_vector_type(8))) short bf16x8;
typedef __attribute__((ext_vector_type(4))) float f32x4;

static __device__ __forceinline__ float b2f(unsigned short u) {
  union { unsigned int i; float f; } c; c.i = ((unsigned int)u) << 16; return c.f;
}
static __device__ __forceinline__ unsigned short f2b(float f) {
  union { float f; unsigned int i; } c; c.f = f;
  unsigned int r = c.i + 0x7FFFu + ((c.i >> 16) & 1u);  // RNE
  return (unsigned short)(r >> 16);
}
static __device__ __forceinline__ unsigned int pack2(float a, float b) {
  return (unsigned int)f2b(a) | ((unsigned int)f2b(b) << 16);
}

__global__ void prep_kernel(
    const float* __restrict__ w0, const float* __restrict__ b0, const float* __restrict__ g0,
    const float* __restrict__ be0, const float* __restrict__ m0, const float* __restrict__ v0,
    const float* __restrict__ w1, const float* __restrict__ b1, const float* __restrict__ g1,
    const float* __restrict__ be1, const float* __restrict__ m1, const float* __restrict__ v1,
    const float* __restrict__ w2, const float* __restrict__ b2, const float* __restrict__ g2,
    const float* __restrict__ be2, const float* __restrict__ m2, const float* __restrict__ v2,
    const float* __restrict__ we0, float* __restrict__ ws) {
  __shared__ float s0[64], s1[64], s2[64];
  int t = threadIdx.x;
  if (t < 64) {
    s0[t] = g0[t] * rsqrtf(v0[t] + 1e-5f);
    s1[t] = g1[t] * rsqrtf(v1[t] + 1e-5f);
    s2[t] = g2[t] * rsqrtf(v2[t] + 1e-5f);
    ws[OFF_B0F + t] = (b0[t] - m0[t]) * s0[t] + be0[t];
    ws[OFF_B1F + t] = (b1[t] - m1[t]) * s1[t] + be1[t];
    ws[OFF_B2F + t] = (b2[t] - m2[t]) * s2[t] + be2[t];
  }
  __syncthreads();
  unsigned short* fr0 = (unsigned short*)(ws + OFF_FR0);
  unsigned short* fr1 = (unsigned short*)(ws + OFF_FR1);
  unsigned short* fr2 = (unsigned short*)(ws + OFF_FR2);
  for (int i = t; i < 2048; i += 256) {  // layer0: KS=1
    int j = i & 7, lane = (i >> 3) & 63, mt = i >> 9;
    int f = mt * 16 + (lane & 15);
    int k = (lane >> 4) * 8 + j;
    fr0[i] = f2b(w0[k * 64 + f] * s0[f]);
  }
  for (int i = t; i < 4096; i += 256) {  // layer1: KS=2
    int j = i & 7, lane = (i >> 3) & 63, tile = i >> 9;
    int mt = tile >> 1, ks = tile & 1;
    int f = mt * 16 + (lane & 15);
    int k = ks * 32 + (lane >> 4) * 8 + j;
    fr1[i] = f2b(w1[k * 64 + f] * s1[f]);
  }
  for (int i = t; i < 4096; i += 256) {  // layer2: KS=2
    int j = i & 7, lane = (i >> 3) & 63, tile = i >> 9;
    int mt = tile >> 1, ks = tile & 1;
    int f = mt * 16 + (lane & 15);
    int k = ks * 32 + (lane >> 4) * 8 + j;
    fr2[i] = f2b(w2[k * 64 + f] * s2[f]);
  }
  unsigned short* fe0 = (unsigned short*)(ws + OFF_FE0);
  for (int i = t; i < 12288; i += 256) {
    int j = i & 7, lane = (i >> 3) & 63, tile = i >> 9;  // tile = mt*3+ks
    int mt = tile / 3, ks = tile - mt * 3;
    int h = mt * 16 + (lane & 15);
    int k = ks * 32 + ((lane >> 4) & 3) * 8 + j;
    fe0[i] = (k < 80) ? f2b(we0[k * 128 + h]) : (unsigned short)0;
  }
}

// ---------- dst-sort pipeline ----------
// Latency-bound kernels (VALU<1%, HBM~15%): batch 4 edges/thread for 4
// independent atomic chains in flight per thread.
__global__ __launch_bounds__(256) void hist_kernel(const int* __restrict__ ei,
                                                   int* __restrict__ counts) {
  int e = blockIdx.x * 1024 + threadIdx.x;
  int d[4];
#pragma unroll
  for (int q = 0; q < 4; ++q) {
    int ee = e + q * 256;
    d[q] = (ee < E_N) ? ei[E_N + ee] : -1;
  }
#pragma unroll
  for (int q = 0; q < 4; ++q)
    if (d[q] >= 0) atomicAdd(&counts[d[q]], 1);
}

__global__ __launch_bounds__(1024) void scan1_kernel(const int* __restrict__ counts,
                                                     int* __restrict__ cursor,
                                                     int* __restrict__ bsum) {
  __shared__ int s[1024];
  int t = threadIdx.x;
  int i = blockIdx.x * 1024 + t;
  int v = (i < N_N) ? counts[i] : 0;
  s[t] = v;
  __syncthreads();
  for (int off = 1; off < 1024; off <<= 1) {
    int a = (t >= off) ? s[t - off] : 0;
    __syncthreads();
    s[t] += a;
    __syncthreads();
  }
  cursor[i] = s[t] - v;  // block-local exclusive
  if (t == 1023) bsum[blockIdx.x] = s[1023];
}

__global__ __launch_bounds__(128) void scan2_kernel(int* __restrict__ bsum) {
  __shared__ int s[128];
  int t = threadIdx.x;
  int v = (t < SCAN_B) ? bsum[t] : 0;
  s[t] = v;
  __syncthreads();
  for (int off = 1; off < 128; off <<= 1) {
    int a = (t >= off) ? s[t - off] : 0;
    __syncthreads();
    s[t] += a;
    __syncthreads();
  }
  if (t < SCAN_B) bsum[t] = s[t] - v;  // exclusive block bases
}

__global__ __launch_bounds__(1024) void scan3_kernel(int* __restrict__ cursor,
                                                     const int* __restrict__ bsum) {
  int i = blockIdx.x * 1024 + threadIdx.x;
  cursor[i] += bsum[blockIdx.x];
}

// R5 store form (two independent 4B stores; nt hint regressed 113->147 us in R7
// by defeating L2 write-combining). 4 edges/thread for atomic-latency MLP.
__global__ __launch_bounds__(256) void scatter_kernel(const int* __restrict__ ei,
                                                      int* __restrict__ cursor,
                                                      int* __restrict__ srcs,
                                                      int* __restrict__ dsts,
                                                      int* __restrict__ ipos) {
  int e = blockIdx.x * 1024 + threadIdx.x;
  int s[4], d[4], p[4];
#pragma unroll
  for (int q = 0; q < 4; ++q) {
    int ee = e + q * 256;
    if (ee < E_N) { s[q] = ei[ee]; d[q] = ei[E_N + ee]; } else d[q] = -1;
  }
#pragma unroll
  for (int q = 0; q < 4; ++q)
    if (d[q] >= 0) p[q] = atomicAdd(&cursor[d[q]], 1);
#pragma unroll
  for (int q = 0; q < 4; ++q) {
    int ee = e + q * 256;
    if (d[q] >= 0) {
      srcs[p[q]] = s[q];
      dsts[p[q]] = d[q];
      ipos[ee] = p[q];
    }
  }
}

// ---------- inner MLP (MFMA), edges in dst-sorted order ----------
template <int KS>
static __device__ __forceinline__ void mfma_layer(
    unsigned short* A, const unsigned short* __restrict__ frag,
    const float* __restrict__ bias, int lane) {
  const int m = lane & 15;
  const int quad = lane >> 4;
  bf16x8 wf[4][KS];
#pragma unroll
  for (int mt = 0; mt < 4; ++mt)
#pragma unroll
    for (int ks = 0; ks < KS; ++ks)
      wf[mt][ks] = *(const bf16x8*)(frag + (((mt * KS + ks) * 64) + lane) * 8);
  f32x4 binit[4];
#pragma unroll
  for (int mt = 0; mt < 4; ++mt)
    binit[mt] = *(const f32x4*)(bias + mt * 16 + quad * 4);
  f32x4 acc[4][4];
#pragma unroll
  for (int mt = 0; mt < 4; ++mt)
#pragma unroll
    for (int nt = 0; nt < 4; ++nt) acc[mt][nt] = binit[mt];
#pragma unroll
  for (int nt = 0; nt < 4; ++nt) {
#pragma unroll
    for (int ks = 0; ks < KS; ++ks) {
      bf16x8 bfr = *(const bf16x8*)(A + (nt * 16 + m) * STR + ks * 32 + quad * 8);
#pragma unroll
      for (int mt = 0; mt < 4; ++mt)
        acc[mt][nt] = __builtin_amdgcn_mfma_f32_16x16x32_bf16(wf[mt][ks], bfr, acc[mt][nt], 0, 0, 0);
    }
  }
  WAVE_SYNC();  // tile is wave-private: drain reads before overwrite
#pragma unroll
  for (int mt = 0; mt < 4; ++mt) {
#pragma unroll
    for (int nt = 0; nt < 4; ++nt) {
      f32x4 a = acc[mt][nt];
      uint2 p;
      p.x = pack2(fmaxf(a.x, 0.f), fmaxf(a.y, 0.f));
      p.y = pack2(fmaxf(a.z, 0.f), fmaxf(a.w, 0.f));
      *(uint2*)(A + (nt * 16 + m) * STR + mt * 16 + quad * 4) = p;
    }
  }
  WAVE_SYNC();
}

__global__ __launch_bounds__(256) void edge_inner_kernel(
    const float* __restrict__ x, const int* __restrict__ srcs, const int* __restrict__ dsts,
    const float* __restrict__ ws, float* __restrict__ yacc) {
  __shared__ unsigned short act[4][64 * STR];
  __shared__ int sdst[256];
  const int tid = threadIdx.x;
  const int w = tid >> 6;
  const int lane = tid & 63;
  unsigned short* A = act[w];

  const int pos = blockIdx.x * 256 + tid;  // E_N % 256 == 0
  const int src = srcs[pos];
  const int dst = dsts[pos];
  sdst[tid] = dst;  // read back only by the same wave

  const float4* x4 = (const float4*)x;
  float4 xi0 = x4[dst * 4 + 0], xi1 = x4[dst * 4 + 1], xi2 = x4[dst * 4 + 2], xi3 = x4[dst * 4 + 3];
  float4 xj0 = x4[src * 4 + 0], xj1 = x4[src * 4 + 1], xj2 = x4[src * 4 + 2], xj3 = x4[src * 4 + 3];
  float vi[16] = {xi0.x, xi0.y, xi0.z, xi0.w, xi1.x, xi1.y, xi1.z, xi1.w,
                  xi2.x, xi2.y, xi2.z, xi2.w, xi3.x, xi3.y, xi3.z, xi3.w};
  float vj[16] = {xj0.x, xj0.y, xj0.z, xj0.w, xj1.x, xj1.y, xj1.z, xj1.w,
                  xj2.x, xj2.y, xj2.z, xj2.w, xj3.x, xj3.y, xj3.z, xj3.w};
  unsigned int* row = (unsigned int*)(A + lane * STR);
#pragma unroll
  for (int q = 0; q < 8; ++q) row[q] = pack2(vi[2 * q], vi[2 * q + 1]);
#pragma unroll
  for (int q = 0; q < 8; ++q)
    row[8 + q] = pack2(vj[2 * q] - vi[2 * q], vj[2 * q + 1] - vi[2 * q + 1]);
  WAVE_SYNC();

  const unsigned short* fr0 = (const unsigned short*)(ws + OFF_FR0);
  const unsigned short* fr1 = (const unsigned short*)(ws + OFF_FR1);
  const unsigned short* fr2 = (const unsigned short*)(ws + OFF_FR2);
  mfma_layer<1>(A, fr0, ws + OFF_B0F, lane);
  mfma_layer<2>(A, fr1, ws + OFF_B1F, lane);
  mfma_layer<2>(A, fr2, ws + OFF_B2F, lane);

  // segment-reduce the wave's 64 sorted edges: one atomic row per dst-run
  const int base = w << 6;
  float sum = 0.f;
  int dprev = sdst[base];
  for (int eo = 0; eo < 64; ++eo) {
    int d = sdst[base + eo];  // wave-uniform
    if (d != dprev) {
      atomicAdd(&yacc[(size_t)dprev * 64 + lane], sum);
      sum = 0.f;
      dprev = d;
    }
    sum += b2f(A[eo * STR + lane]);
  }
  atomicAdd(&yacc[(size_t)dprev * 64 + lane], sum);
}

__global__ __launch_bounds__(256) void node_kernel(
    const float* __restrict__ yacc, const int* __restrict__ counts,
    const float* __restrict__ x, unsigned short* __restrict__ ybf) {
  int idx = blockIdx.x * 256 + threadIdx.x;
  if (idx >= N_N * 80) return;
  int n = idx / 80;
  int j = idx - n * 80;
  float v;
  if (j < 64) v = yacc[(size_t)n * 64 + j] / fmaxf((float)counts[n], 1.0f);
  else        v = x[n * 16 + (j - 64)];
  ybf[idx] = f2b(fmaxf(v, 0.f));
}

// MFMA end-MLP in sorted order; writes pre-sigmoid z coalesced to zperm
__global__ __launch_bounds__(256) void edge_out_kernel(
    const unsigned short* __restrict__ ybf,
    const int* __restrict__ srcs, const int* __restrict__ dsts,
    const unsigned short* __restrict__ fe0, const float* __restrict__ bee0,
    const float* __restrict__ we1, const float* __restrict__ bee1,
    float* __restrict__ zperm) {
  __shared__ unsigned short Dt[4][64 * OSTR];
  const int tid = threadIdx.x, w = tid >> 6, lane = tid & 63;
  const int quad = lane >> 4, m = lane & 15;
  unsigned short* Dw = Dt[w];
  const int pos = blockIdx.x * 256 + tid;
  const int src = srcs[pos], dst = dsts[pos];
  const bf16x8* ps = (const bf16x8*)(ybf + (size_t)src * 80);
  const bf16x8* pd = (const bf16x8*)(ybf + (size_t)dst * 80);
  uint4* drow = (uint4*)(Dw + lane * OSTR);
#pragma unroll
  for (int q = 0; q < 10; ++q) {  // 80 feats = 10 bf16x8 loads
    bf16x8 a = ps[q], b = pd[q];
    uint4 p;
    p.x = pack2(b2f((unsigned short)a[0]) - b2f((unsigned short)b[0]),
                b2f((unsigned short)a[1]) - b2f((unsigned short)b[1]));
    p.y = pack2(b2f((unsigned short)a[2]) - b2f((unsigned short)b[2]),
                b2f((unsigned short)a[3]) - b2f((unsigned short)b[3]));
    p.z = pack2(b2f((unsigned short)a[4]) - b2f((unsigned short)b[4]),
                b2f((unsigned short)a[5]) - b2f((unsigned short)b[5]));
    p.w = pack2(b2f((unsigned short)a[6]) - b2f((unsigned short)b[6]),
                b2f((unsigned short)a[7]) - b2f((unsigned short)b[7]));
    drow[q] = p;
  }
  { uint4 z; z.x = z.y = z.z = z.w = 0u; drow[10] = z; drow[11] = z; }  // pad k=80..95
  WAVE_SYNC();  // Dt[w] is wave-private

  bf16x8 bf[4][3];
#pragma unroll
  for (int nt = 0; nt < 4; ++nt)
#pragma unroll
    for (int ks = 0; ks < 3; ++ks)
      bf[nt][ks] = *(const bf16x8*)(Dw + (nt * 16 + m) * OSTR + ks * 32 + quad * 8);

  float fin[4] = {0.f, 0.f, 0.f, 0.f};
  for (int mt = 0; mt < 8; ++mt) {
    bf16x8 wf[3];
#pragma unroll
    for (int ks = 0; ks < 3; ++ks)
      wf[ks] = *(const bf16x8*)(fe0 + (size_t)(((mt * 3 + ks) * 64) + lane) * 8);
    f32x4 binit = *(const f32x4*)(bee0 + mt * 16 + quad * 4);
    float4 w1v = *(const float4*)(we1 + mt * 16 + quad * 4);
    f32x4 acc[4];
#pragma unroll
    for (int nt = 0; nt < 4; ++nt) acc[nt] = binit;
#pragma unroll
    for (int nt = 0; nt < 4; ++nt)
#pragma unroll
      for (int ks = 0; ks < 3; ++ks)
        acc[nt] = __builtin_amdgcn_mfma_f32_16x16x32_bf16(wf[ks], bf[nt][ks], acc[nt], 0, 0, 0);
#pragma unroll
    for (int nt = 0; nt < 4; ++nt) {
      f32x4 a = acc[nt];
      fin[nt] += fmaxf(a.x, 0.f) * w1v.x + fmaxf(a.y, 0.f) * w1v.y +
                 fmaxf(a.z, 0.f) * w1v.z + fmaxf(a.w, 0.f) * w1v.w;
    }
  }
#pragma unroll
  for (int nt = 0; nt < 4; ++nt) {
    float v = fin[nt];
    v += __shfl_xor(v, 16);
    v += __shfl_xor(v, 32);
    fin[nt] = v;
  }
  float z = (quad == 0) ? fin[0] : (quad == 1) ? fin[1] : (quad == 2) ? fin[2] : fin[3];
  zperm[pos] = z + bee1[0];
}

__global__ __launch_bounds__(256) void unperm_kernel(const float* __restrict__ zperm,
                                                     const int* __restrict__ ipos,
                                                     float* __restrict__ out) {
  int e = blockIdx.x * 256 + threadIdx.x;
  if (e >= E_N) return;
  float z = zperm[ipos[e]];
  out[e] = 1.0f / (1.0f + __expf(-z));
}

extern "C" void kernel_launch(void* const* d_in, const int* in_sizes, int n_in,
                              void* d_out, int out_size, void* d_ws, size_t ws_size,
                              hipStream_t stream) {
  const float* x   = (const float*)d_in[0];
  const int* ei    = (const int*)d_in[1];
  const float* w0  = (const float*)d_in[2];
  const float* b0  = (const float*)d_in[3];
  const float* g0  = (const float*)d_in[4];
  const float* be0 = (const float*)d_in[5];
  const float* m0  = (const float*)d_in[6];
  const float* v0  = (const float*)d_in[7];
  const float* w1  = (const float*)d_in[8];
  const float* b1  = (const float*)d_in[9];
  const float* g1  = (const float*)d_in[10];
  const float* be1 = (const float*)d_in[11];
  const float* m1  = (const float*)d_in[12];
  const float* v1  = (const float*)d_in[13];
  const float* w2  = (const float*)d_in[14];
  const float* b2  = (const float*)d_in[15];
  const float* g2  = (const float*)d_in[16];
  const float* be2 = (const float*)d_in[17];
  const float* m2  = (const float*)d_in[18];
  const float* v2  = (const float*)d_in[19];
  const float* we0 = (const float*)d_in[20];
  const float* bee0= (const float*)d_in[21];
  const float* we1 = (const float*)d_in[22];
  const float* bee1= (const float*)d_in[23];
  float* out = (float*)d_out;
  float* ws  = (float*)d_ws;

  int* counts = (int*)(ws + OFF_CNT);
  int* cursor = (int*)(ws + OFF_CUR);
  int* bsum   = (int*)(ws + OFF_BSUM);
  int* srcs   = (int*)(ws + OFF_SRCS);
  int* dsts   = (int*)(ws + OFF_DSTS);
  int* ipos   = (int*)(ws + OFF_IPOS);
  float* zperm = ws + OFF_YACC;  // aliases yacc: dead after node_kernel

  hipMemsetAsync(ws + OFF_YACC, 0, (size_t)N_N * 64 * sizeof(float), stream);
  hipMemsetAsync(counts, 0, (size_t)N_N * sizeof(int), stream);
  prep_kernel<<<1, 256, 0, stream>>>(w0, b0, g0, be0, m0, v0,
                                     w1, b1, g1, be1, m1, v1,
                                     w2, b2, g2, be2, m2, v2, we0, ws);
  hist_kernel<<<(E_N + 1023) / 1024, 256, 0, stream>>>(ei, counts);
  scan1_kernel<<<SCAN_B, 1024, 0, stream>>>(counts, cursor, bsum);
  scan2_kernel<<<1, 128, 0, stream>>>(bsum);
  scan3_kernel<<<SCAN_B, 1024, 0, stream>>>(cursor, bsum);
  scatter_kernel<<<(E_N + 1023) / 1024, 256, 0, stream>>>(ei, cursor, srcs, dsts, ipos);
  edge_inner_kernel<<<E_N / 256, 256, 0, stream>>>(x, srcs, dsts, ws, ws + OFF_YACC);
  node_kernel<<<(N_N * 80 + 255) / 256, 256, 0, stream>>>(ws + OFF_YACC, counts, x,
                                                          (unsigned short*)(ws + OFF_YBF));
  edge_out_kernel<<<E_N / 256, 256, 0, stream>>>((const unsigned short*)(ws + OFF_YBF),
                                                 srcs, dsts,
                                                 (const unsigned short*)(ws + OFF_FE0),
                                                 bee0, we1, bee1, zperm);
  unperm_kernel<<<(E_N + 255) / 256, 256, 0, stream>>>(zperm, ipos, out);
}

// Round 9
// 492.660 us; speedup vs baseline: 1.1325x; 1.0421x over previous
//
#include <hip/hip_runtime.h>

#define E_N 1600000
#define N_N 100000
#define SCAN_B 98  // ceil(N_N/1024)

// d_ws float-offset layout (same 61.6 MB footprint as R8)
#define OFF_B0F  0
#define OFF_B1F  64
#define OFF_B2F  128
#define OFF_FR0  192       // inner layer0 A-frags: 2048 bf16
#define OFF_FR1  1216      // 4096 bf16
#define OFF_FR2  3264      // 4096 bf16
#define OFF_FE0  5312      // we0^T A-frags: 12288 bf16 (K padded 80->96)
#define OFF_ZPERM 11456    // E floats (pre-sigmoid z, sorted order)
#define OFF_YACC 4011456   // N*64 fp32 agg accumulator; h (N*128 bf16) overlays it byte-exact
#define OFF_CNT  10411456  // N ints (in-degree histogram)
#define OFF_CUR  10511456  // 100352 ints
#define OFF_BSUM 10611808  // 128 ints
#define OFF_SRCS 10611936  // E ints
#define OFF_DSTS 12211936  // E ints
#define OFF_IPOS 13811936  // E ints
// total = 15,411,936 floats ≈ 61.6 MB

#define STR 72   // inner LDS activation row stride (bf16)
#define OSTR 104 // h_gemm LDS row stride (bf16): 96 used + 8 pad

#define WAVE_SYNC() __asm__ volatile("s_waitcnt lgkmcnt(0)" ::: "memory")

typedef __attribute__((ext_vector_type(8))) short bf16x8;
typedef __attribute__((ext_vector_type(4))) float f32x4;

static __device__ __forceinline__ float b2f(unsigned short u) {
  union { unsigned int i; float f; } c; c.i = ((unsigned int)u) << 16; return c.f;
}
static __device__ __forceinline__ float asf(unsigned int u) {
  union { unsigned int i; float f; } c; c.i = u; return c.f;
}
static __device__ __forceinline__ unsigned short f2b(float f) {
  union { float f; unsigned int i; } c; c.f = f;
  unsigned int r = c.i + 0x7FFFu + ((c.i >> 16) & 1u);  // RNE
  return (unsigned short)(r >> 16);
}
static __device__ __forceinline__ unsigned int pack2(float a, float b) {
  return (unsigned int)f2b(a) | ((unsigned int)f2b(b) << 16);
}

__global__ void prep_kernel(
    const float* __restrict__ w0, const float* __restrict__ b0, const float* __restrict__ g0,
    const float* __restrict__ be0, const float* __restrict__ m0, const float* __restrict__ v0,
    const float* __restrict__ w1, const float* __restrict__ b1, const float* __restrict__ g1,
    const float* __restrict__ be1, const float* __restrict__ m1, const float* __restrict__ v1,
    const float* __restrict__ w2, const float* __restrict__ b2, const float* __restrict__ g2,
    const float* __restrict__ be2, const float* __restrict__ m2, const float* __restrict__ v2,
    const float* __restrict__ we0, float* __restrict__ ws) {
  __shared__ float s0[64], s1[64], s2[64];
  int t = threadIdx.x;
  if (t < 64) {
    s0[t] = g0[t] * rsqrtf(v0[t] + 1e-5f);
    s1[t] = g1[t] * rsqrtf(v1[t] + 1e-5f);
    s2[t] = g2[t] * rsqrtf(v2[t] + 1e-5f);
    ws[OFF_B0F + t] = (b0[t] - m0[t]) * s0[t] + be0[t];
    ws[OFF_B1F + t] = (b1[t] - m1[t]) * s1[t] + be1[t];
    ws[OFF_B2F + t] = (b2[t] - m2[t]) * s2[t] + be2[t];
  }
  __syncthreads();
  unsigned short* fr0 = (unsigned short*)(ws + OFF_FR0);
  unsigned short* fr1 = (unsigned short*)(ws + OFF_FR1);
  unsigned short* fr2 = (unsigned short*)(ws + OFF_FR2);
  for (int i = t; i < 2048; i += 256) {  // layer0: KS=1
    int j = i & 7, lane = (i >> 3) & 63, mt = i >> 9;
    int f = mt * 16 + (lane & 15);
    int k = (lane >> 4) * 8 + j;
    fr0[i] = f2b(w0[k * 64 + f] * s0[f]);
  }
  for (int i = t; i < 4096; i += 256) {  // layer1: KS=2
    int j = i & 7, lane = (i >> 3) & 63, tile = i >> 9;
    int mt = tile >> 1, ks = tile & 1;
    int f = mt * 16 + (lane & 15);
    int k = ks * 32 + (lane >> 4) * 8 + j;
    fr1[i] = f2b(w1[k * 64 + f] * s1[f]);
  }
  for (int i = t; i < 4096; i += 256) {  // layer2: KS=2
    int j = i & 7, lane = (i >> 3) & 63, tile = i >> 9;
    int mt = tile >> 1, ks = tile & 1;
    int f = mt * 16 + (lane & 15);
    int k = ks * 32 + (lane >> 4) * 8 + j;
    fr2[i] = f2b(w2[k * 64 + f] * s2[f]);
  }
  // we0^T A-frags: h = mt*16+(lane&15), k = ks*32+((lane>>4)&3)*8+j, zero k>=80
  unsigned short* fe0 = (unsigned short*)(ws + OFF_FE0);
  for (int i = t; i < 12288; i += 256) {
    int j = i & 7, lane = (i >> 3) & 63, tile = i >> 9;  // tile = mt*3+ks
    int mt = tile / 3, ks = tile - mt * 3;
    int h = mt * 16 + (lane & 15);
    int k = ks * 32 + ((lane >> 4) & 3) * 8 + j;
    fe0[i] = (k < 80) ? f2b(we0[k * 128 + h]) : (unsigned short)0;
  }
}

// ---------- dst-sort pipeline (R8-verified forms) ----------
__global__ __launch_bounds__(256) void hist_kernel(const int* __restrict__ ei,
                                                   int* __restrict__ counts) {
  int e = blockIdx.x * 1024 + threadIdx.x;
  int d[4];
#pragma unroll
  for (int q = 0; q < 4; ++q) {
    int ee = e + q * 256;
    d[q] = (ee < E_N) ? ei[E_N + ee] : -1;
  }
#pragma unroll
  for (int q = 0; q < 4; ++q)
    if (d[q] >= 0) atomicAdd(&counts[d[q]], 1);
}

__global__ __launch_bounds__(1024) void scan1_kernel(const int* __restrict__ counts,
                                                     int* __restrict__ cursor,
                                                     int* __restrict__ bsum) {
  __shared__ int s[1024];
  int t = threadIdx.x;
  int i = blockIdx.x * 1024 + t;
  int v = (i < N_N) ? counts[i] : 0;
  s[t] = v;
  __syncthreads();
  for (int off = 1; off < 1024; off <<= 1) {
    int a = (t >= off) ? s[t - off] : 0;
    __syncthreads();
    s[t] += a;
    __syncthreads();
  }
  cursor[i] = s[t] - v;
  if (t == 1023) bsum[blockIdx.x] = s[1023];
}

__global__ __launch_bounds__(128) void scan2_kernel(int* __restrict__ bsum) {
  __shared__ int s[128];
  int t = threadIdx.x;
  int v = (t < SCAN_B) ? bsum[t] : 0;
  s[t] = v;
  __syncthreads();
  for (int off = 1; off < 128; off <<= 1) {
    int a = (t >= off) ? s[t - off] : 0;
    __syncthreads();
    s[t] += a;
    __syncthreads();
  }
  if (t < SCAN_B) bsum[t] = s[t] - v;
}

__global__ __launch_bounds__(1024) void scan3_kernel(int* __restrict__ cursor,
                                                     const int* __restrict__ bsum) {
  int i = blockIdx.x * 1024 + threadIdx.x;
  cursor[i] += bsum[blockIdx.x];
}

__global__ __launch_bounds__(256) void scatter_kernel(const int* __restrict__ ei,
                                                      int* __restrict__ cursor,
                                                      int* __restrict__ srcs,
                                                      int* __restrict__ dsts,
                                                      int* __restrict__ ipos) {
  int e = blockIdx.x * 1024 + threadIdx.x;
  int s[4], d[4], p[4];
#pragma unroll
  for (int q = 0; q < 4; ++q) {
    int ee = e + q * 256;
    if (ee < E_N) { s[q] = ei[ee]; d[q] = ei[E_N + ee]; } else d[q] = -1;
  }
#pragma unroll
  for (int q = 0; q < 4; ++q)
    if (d[q] >= 0) p[q] = atomicAdd(&cursor[d[q]], 1);
#pragma unroll
  for (int q = 0; q < 4; ++q) {
    int ee = e + q * 256;
    if (d[q] >= 0) {
      srcs[p[q]] = s[q];
      dsts[p[q]] = d[q];
      ipos[ee] = p[q];
    }
  }
}

// ---------- inner MLP (MFMA), edges in dst-sorted order ----------
template <int KS>
static __device__ __forceinline__ void mfma_layer(
    unsigned short* A, const unsigned short* __restrict__ frag,
    const float* __restrict__ bias, int lane) {
  const int m = lane & 15;
  const int quad = lane >> 4;
  bf16x8 wf[4][KS];
#pragma unroll
  for (int mt = 0; mt < 4; ++mt)
#pragma unroll
    for (int ks = 0; ks < KS; ++ks)
      wf[mt][ks] = *(const bf16x8*)(frag + (((mt * KS + ks) * 64) + lane) * 8);
  f32x4 binit[4];
#pragma unroll
  for (int mt = 0; mt < 4; ++mt)
    binit[mt] = *(const f32x4*)(bias + mt * 16 + quad * 4);
  f32x4 acc[4][4];
#pragma unroll
  for (int mt = 0; mt < 4; ++mt)
#pragma unroll
    for (int nt = 0; nt < 4; ++nt) acc[mt][nt] = binit[mt];
#pragma unroll
  for (int nt = 0; nt < 4; ++nt) {
#pragma unroll
    for (int ks = 0; ks < KS; ++ks) {
      bf16x8 bfr = *(const bf16x8*)(A + (nt * 16 + m) * STR + ks * 32 + quad * 8);
#pragma unroll
      for (int mt = 0; mt < 4; ++mt)
        acc[mt][nt] = __builtin_amdgcn_mfma_f32_16x16x32_bf16(wf[mt][ks], bfr, acc[mt][nt], 0, 0, 0);
    }
  }
  WAVE_SYNC();
#pragma unroll
  for (int mt = 0; mt < 4; ++mt) {
#pragma unroll
    for (int nt = 0; nt < 4; ++nt) {
      f32x4 a = acc[mt][nt];
      uint2 p;
      p.x = pack2(fmaxf(a.x, 0.f), fmaxf(a.y, 0.f));
      p.y = pack2(fmaxf(a.z, 0.f), fmaxf(a.w, 0.f));
      *(uint2*)(A + (nt * 16 + m) * STR + mt * 16 + quad * 4) = p;
    }
  }
  WAVE_SYNC();
}

__global__ __launch_bounds__(256) void edge_inner_kernel(
    const float* __restrict__ x, const int* __restrict__ srcs, const int* __restrict__ dsts,
    const float* __restrict__ ws, float* __restrict__ yacc) {
  __shared__ unsigned short act[4][64 * STR];
  const int tid = threadIdx.x;
  const int w = tid >> 6;
  const int lane = tid & 63;
  unsigned short* A = act[w];

  const int pos = blockIdx.x * 256 + tid;  // E_N % 256 == 0
  const int src = srcs[pos];
  const int dst = dsts[pos];
  // run-start mask from registers (wave-uniform after ballot)
  unsigned long long runmask = __ballot((lane == 0) || (dst != __shfl_up(dst, 1)));

  const float4* x4 = (const float4*)x;
  float4 xi0 = x4[dst * 4 + 0], xi1 = x4[dst * 4 + 1], xi2 = x4[dst * 4 + 2], xi3 = x4[dst * 4 + 3];
  float4 xj0 = x4[src * 4 + 0], xj1 = x4[src * 4 + 1], xj2 = x4[src * 4 + 2], xj3 = x4[src * 4 + 3];
  float vi[16] = {xi0.x, xi0.y, xi0.z, xi0.w, xi1.x, xi1.y, xi1.z, xi1.w,
                  xi2.x, xi2.y, xi2.z, xi2.w, xi3.x, xi3.y, xi3.z, xi3.w};
  float vj[16] = {xj0.x, xj0.y, xj0.z, xj0.w, xj1.x, xj1.y, xj1.z, xj1.w,
                  xj2.x, xj2.y, xj2.z, xj2.w, xj3.x, xj3.y, xj3.z, xj3.w};
  unsigned int* row = (unsigned int*)(A + lane * STR);
#pragma unroll
  for (int q = 0; q < 8; ++q) row[q] = pack2(vi[2 * q], vi[2 * q + 1]);
#pragma unroll
  for (int q = 0; q < 8; ++q)
    row[8 + q] = pack2(vj[2 * q] - vi[2 * q], vj[2 * q + 1] - vi[2 * q + 1]);
  WAVE_SYNC();

  const unsigned short* fr0 = (const unsigned short*)(ws + OFF_FR0);
  const unsigned short* fr1 = (const unsigned short*)(ws + OFF_FR1);
  const unsigned short* fr2 = (const unsigned short*)(ws + OFF_FR2);
  mfma_layer<1>(A, fr0, ws + OFF_B0F, lane);
  mfma_layer<2>(A, fr1, ws + OFF_B1F, lane);
  mfma_layer<2>(A, fr2, ws + OFF_B2F, lane);

  // segment-reduce via scalar run loop (no per-edge dst loads/compares)
  while (runmask) {
    int a = __ffsll(runmask) - 1;
    runmask &= runmask - 1;
    int b = runmask ? (__ffsll(runmask) - 1) : 64;
    float sum = 0.f;
    for (int eo = a; eo < b; ++eo) sum += b2f(A[eo * STR + lane]);
    int d = __shfl(dst, a);
    atomicAdd(&yacc[(size_t)d * 64 + lane], sum);
  }
}

// Fused node-normalize + relu + concat-x + GEMM(y@we0) -> h bf16.
// h overlays yacc byte-exact per node (N*64 f32 == N*128 bf16); each wave
// reads then writes only its own 64-node range -> safe in-place.
__global__ __launch_bounds__(256) void h_gemm_kernel(
    const float* __restrict__ yacc, const int* __restrict__ counts,
    const float* __restrict__ x, const unsigned short* __restrict__ fe0,
    unsigned short* __restrict__ hout) {
  __shared__ unsigned short Yt[4][64 * OSTR];
  const int tid = threadIdx.x, w = tid >> 6, lane = tid & 63;
  const int quad = lane >> 4, m = lane & 15;
  unsigned short* Aw = Yt[w];
  const int tb = (blockIdx.x * 4 + w) * 64;
  const int node = tb + lane;
  unsigned short* rowp = Aw + lane * OSTR;
  if (node < N_N) {
    float inv = 1.0f / fmaxf((float)counts[node], 1.0f);
    const float4* ya = (const float4*)(yacc + (size_t)node * 64);
#pragma unroll
    for (int q = 0; q < 16; ++q) {
      float4 t = ya[q];
      uint2 p;
      p.x = pack2(fmaxf(t.x * inv, 0.f), fmaxf(t.y * inv, 0.f));
      p.y = pack2(fmaxf(t.z * inv, 0.f), fmaxf(t.w * inv, 0.f));
      *(uint2*)(rowp + q * 4) = p;
    }
    const float4* xx = (const float4*)(x + (size_t)node * 16);
#pragma unroll
    for (int q = 0; q < 4; ++q) {
      float4 t = xx[q];
      uint2 p;
      p.x = pack2(fmaxf(t.x, 0.f), fmaxf(t.y, 0.f));
      p.y = pack2(fmaxf(t.z, 0.f), fmaxf(t.w, 0.f));
      *(uint2*)(rowp + 64 + q * 4) = p;
    }
  } else {
    uint4 z; z.x = z.y = z.z = z.w = 0u;
#pragma unroll
    for (int q = 0; q < 10; ++q) *(uint4*)(rowp + q * 8) = z;
  }
  { uint4 z; z.x = z.y = z.z = z.w = 0u;
    *(uint4*)(rowp + 80) = z; *(uint4*)(rowp + 88) = z; }  // pad k=80..95
  WAVE_SYNC();

  bf16x8 bfr[4][3];
#pragma unroll
  for (int nt = 0; nt < 4; ++nt)
#pragma unroll
    for (int ks = 0; ks < 3; ++ks)
      bfr[nt][ks] = *(const bf16x8*)(Aw + (nt * 16 + m) * OSTR + ks * 32 + quad * 8);

  for (int mt = 0; mt < 8; ++mt) {
    bf16x8 wf[3];
#pragma unroll
    for (int ks = 0; ks < 3; ++ks)
      wf[ks] = *(const bf16x8*)(fe0 + (size_t)(((mt * 3 + ks) * 64) + lane) * 8);
    f32x4 acc[4];
#pragma unroll
    for (int nt = 0; nt < 4; ++nt) { acc[nt].x = 0.f; acc[nt].y = 0.f; acc[nt].z = 0.f; acc[nt].w = 0.f; }
#pragma unroll
    for (int nt = 0; nt < 4; ++nt)
#pragma unroll
      for (int ks = 0; ks < 3; ++ks)
        acc[nt] = __builtin_amdgcn_mfma_f32_16x16x32_bf16(wf[ks], bfr[nt][ks], acc[nt], 0, 0, 0);
#pragma unroll
    for (int nt = 0; nt < 4; ++nt) {
      int n2 = tb + nt * 16 + m;
      if (n2 < N_N) {
        f32x4 a = acc[nt];
        uint2 p;
        p.x = pack2(a.x, a.y);
        p.y = pack2(a.z, a.w);
        *(uint2*)(hout + (size_t)n2 * 128 + mt * 16 + quad * 4) = p;
      }
    }
  }
}

// Per-edge end-MLP via linearity: z = bee1 + sum_j relu(h_s[j]-h_d[j]+bee0[j])*we1[j]
__global__ __launch_bounds__(256) void edge_z_kernel(
    const unsigned short* __restrict__ h,
    const int* __restrict__ srcs, const int* __restrict__ dsts,
    const float* __restrict__ bee0, const float* __restrict__ we1,
    const float* __restrict__ bee1, float* __restrict__ zperm) {
  const int pos = blockIdx.x * 256 + threadIdx.x;
  const int src = srcs[pos], dst = dsts[pos];
  const uint4* ph_s = (const uint4*)(h + (size_t)src * 128);
  const uint4* ph_d = (const uint4*)(h + (size_t)dst * 128);
  float z0 = 0.f, z1 = 0.f, z2 = 0.f, z3 = 0.f;
#pragma unroll 4
  for (int c = 0; c < 16; ++c) {
    uint4 a = ph_s[c], b = ph_d[c];
    const float4 be_a = *(const float4*)(bee0 + c * 8);
    const float4 be_b = *(const float4*)(bee0 + c * 8 + 4);
    const float4 w_a = *(const float4*)(we1 + c * 8);
    const float4 w_b = *(const float4*)(we1 + c * 8 + 4);
    float v;
    v = fmaxf(asf(a.x << 16) - asf(b.x << 16) + be_a.x, 0.f);          z0 = fmaf(v, w_a.x, z0);
    v = fmaxf(asf(a.x & 0xffff0000u) - asf(b.x & 0xffff0000u) + be_a.y, 0.f); z1 = fmaf(v, w_a.y, z1);
    v = fmaxf(asf(a.y << 16) - asf(b.y << 16) + be_a.z, 0.f);          z2 = fmaf(v, w_a.z, z2);
    v = fmaxf(asf(a.y & 0xffff0000u) - asf(b.y & 0xffff0000u) + be_a.w, 0.f); z3 = fmaf(v, w_a.w, z3);
    v = fmaxf(asf(a.z << 16) - asf(b.z << 16) + be_b.x, 0.f);          z0 = fmaf(v, w_b.x, z0);
    v = fmaxf(asf(a.z & 0xffff0000u) - asf(b.z & 0xffff0000u) + be_b.y, 0.f); z1 = fmaf(v, w_b.y, z1);
    v = fmaxf(asf(a.w << 16) - asf(b.w << 16) + be_b.z, 0.f);          z2 = fmaf(v, w_b.z, z2);
    v = fmaxf(asf(a.w & 0xffff0000u) - asf(b.w & 0xffff0000u) + be_b.w, 0.f); z3 = fmaf(v, w_b.w, z3);
  }
  zperm[pos] = ((z0 + z1) + (z2 + z3)) + bee1[0];
}

__global__ __launch_bounds__(256) void unperm_kernel(const float* __restrict__ zperm,
                                                     const int* __restrict__ ipos,
                                                     float* __restrict__ out) {
  int e = blockIdx.x * 256 + threadIdx.x;
  if (e >= E_N) return;
  float z = zperm[ipos[e]];
  out[e] = 1.0f / (1.0f + __expf(-z));
}

extern "C" void kernel_launch(void* const* d_in, const int* in_sizes, int n_in,
                              void* d_out, int out_size, void* d_ws, size_t ws_size,
                              hipStream_t stream) {
  const float* x   = (const float*)d_in[0];
  const int* ei    = (const int*)d_in[1];
  const float* w0  = (const float*)d_in[2];
  const float* b0  = (const float*)d_in[3];
  const float* g0  = (const float*)d_in[4];
  const float* be0 = (const float*)d_in[5];
  const float* m0  = (const float*)d_in[6];
  const float* v0  = (const float*)d_in[7];
  const float* w1  = (const float*)d_in[8];
  const float* b1  = (const float*)d_in[9];
  const float* g1  = (const float*)d_in[10];
  const float* be1 = (const float*)d_in[11];
  const float* m1  = (const float*)d_in[12];
  const float* v1  = (const float*)d_in[13];
  const float* w2  = (const float*)d_in[14];
  const float* b2  = (const float*)d_in[15];
  const float* g2  = (const float*)d_in[16];
  const float* be2 = (const float*)d_in[17];
  const float* m2  = (const float*)d_in[18];
  const float* v2  = (const float*)d_in[19];
  const float* we0 = (const float*)d_in[20];
  const float* bee0= (const float*)d_in[21];
  const float* we1 = (const float*)d_in[22];
  const float* bee1= (const float*)d_in[23];
  float* out = (float*)d_out;
  float* ws  = (float*)d_ws;

  int* counts = (int*)(ws + OFF_CNT);
  int* cursor = (int*)(ws + OFF_CUR);
  int* bsum   = (int*)(ws + OFF_BSUM);
  int* srcs   = (int*)(ws + OFF_SRCS);
  int* dsts   = (int*)(ws + OFF_DSTS);
  int* ipos   = (int*)(ws + OFF_IPOS);
  float* zperm = ws + OFF_ZPERM;
  unsigned short* h = (unsigned short*)(ws + OFF_YACC);  // overlays yacc

  hipMemsetAsync(ws + OFF_YACC, 0, (size_t)N_N * 64 * sizeof(float), stream);
  hipMemsetAsync(counts, 0, (size_t)N_N * sizeof(int), stream);
  prep_kernel<<<1, 256, 0, stream>>>(w0, b0, g0, be0, m0, v0,
                                     w1, b1, g1, be1, m1, v1,
                                     w2, b2, g2, be2, m2, v2, we0, ws);
  hist_kernel<<<(E_N + 1023) / 1024, 256, 0, stream>>>(ei, counts);
  scan1_kernel<<<SCAN_B, 1024, 0, stream>>>(counts, cursor, bsum);
  scan2_kernel<<<1, 128, 0, stream>>>(bsum);
  scan3_kernel<<<SCAN_B, 1024, 0, stream>>>(cursor, bsum);
  scatter_kernel<<<(E_N + 1023) / 1024, 256, 0, stream>>>(ei, cursor, srcs, dsts, ipos);
  edge_inner_kernel<<<E_N / 256, 256, 0, stream>>>(x, srcs, dsts, ws, ws + OFF_YACC);
  h_gemm_kernel<<<(N_N + 255) / 256, 256, 0, stream>>>(ws + OFF_YACC, counts, x,
                                                       (const unsigned short*)(ws + OFF_FE0), h);
  edge_z_kernel<<<E_N / 256, 256, 0, stream>>>(h, srcs, dsts, bee0, we1, bee1, zperm);
  unperm_kernel<<<(E_N + 255) / 256, 256, 0, stream>>>(zperm, ipos, out);
}